// Round 1
// baseline (798.056 us; speedup 1.0000x reference)
//
#include <hip/hip_runtime.h>

#define THREADS 256
#define ROWS_PER_BLOCK 256
#define ROW 25
#define TILE_FLOATS (ROWS_PER_BLOCK * ROW)   // 6400, divisible by 4
#define TILE_VEC4 (TILE_FLOATS / 4)          // 1600

__launch_bounds__(THREADS)
__global__ void loss_soft_add_kernel(const float* __restrict__ pre,
                                     const float* __restrict__ tar,
                                     float* __restrict__ out, int B) {
    __shared__ float s_pre[TILE_FLOATS];
    __shared__ float s_tar[TILE_FLOATS];
    __shared__ float s_part[THREADS / 64];

    const int tid  = threadIdx.x;
    const int row0 = blockIdx.x * ROWS_PER_BLOCK;
    const int nrows = min(ROWS_PER_BLOCK, B - row0);
    const int nfloats = nrows * ROW;

    const size_t base = (size_t)row0 * ROW;   // divisible by 4 (row0 % 4 == 0)

    if (nfloats == TILE_FLOATS) {
        // Full tile: vectorized float4 staging (base element index divisible by 4,
        // global base pointer 256B-aligned -> 16B-aligned vec loads).
        const float4* gp = (const float4*)(pre + base);
        const float4* gt = (const float4*)(tar + base);
        float4* sp = (float4*)s_pre;
        float4* st = (float4*)s_tar;
        #pragma unroll
        for (int k = 0; k < (TILE_VEC4 + THREADS - 1) / THREADS; ++k) {
            int idx = tid + k * THREADS;
            if (idx < TILE_VEC4) {
                sp[idx] = gp[idx];
                st[idx] = gt[idx];
            }
        }
    } else {
        // Tail tile (not hit for B = 4,000,000, but keep it correct).
        for (int idx = tid; idx < nfloats; idx += THREADS) {
            s_pre[idx] = pre[base + idx];
            s_tar[idx] = tar[base + idx];
        }
    }
    __syncthreads();

    float acc = 0.0f;
    if (tid < nrows) {
        const float* rp = &s_pre[tid * ROW];
        const float* rt = &s_tar[tid * ROW];
        float total = 0.0f;
        #pragma unroll
        for (int c = 0; c < 6; ++c) {
            float x0 = rp[c * 4 + 0];
            float x1 = rp[c * 4 + 1];
            float x2 = rp[c * 4 + 2];
            float x3 = rp[c * 4 + 3];
            float m = fmaxf(fmaxf(x0, x1), fmaxf(x2, x3));
            float e0 = __expf(x0 - m);
            float e1 = __expf(x1 - m);
            float e2 = __expf(x2 - m);
            float e3 = __expf(x3 - m);
            float k = 3.0f / (e0 + e1 + e2 + e3);
            total += fabsf(e0 * k - rt[c * 4 + 0]);
            total += fabsf(e1 * k - rt[c * 4 + 1]);
            total += fabsf(e2 * k - rt[c * 4 + 2]);
            total += fabsf(e3 * k - rt[c * 4 + 3]);
        }
        acc = total * (1.0f / 24.0f);
    }

    // Wave (64-lane) reduction, then cross-wave via LDS, one atomic per block.
    #pragma unroll
    for (int off = 32; off > 0; off >>= 1)
        acc += __shfl_down(acc, off, 64);
    const int wid = tid >> 6, lane = tid & 63;
    if (lane == 0) s_part[wid] = acc;
    __syncthreads();
    if (tid == 0) {
        float bsum = s_part[0] + s_part[1] + s_part[2] + s_part[3];
        atomicAdd(out, bsum);
    }
}

extern "C" void kernel_launch(void* const* d_in, const int* in_sizes, int n_in,
                              void* d_out, int out_size, void* d_ws, size_t ws_size,
                              hipStream_t stream) {
    const float* pre = (const float*)d_in[0];
    const float* tar = (const float*)d_in[1];
    float* out = (float*)d_out;
    const int B = in_sizes[0] / ROW;   // 4,000,000

    // d_out is re-poisoned to 0xAA before every launch; zero it on-stream.
    hipMemsetAsync(d_out, 0, sizeof(float) * out_size, stream);

    const int blocks = (B + ROWS_PER_BLOCK - 1) / ROWS_PER_BLOCK;  // 15625
    loss_soft_add_kernel<<<blocks, THREADS, 0, stream>>>(pre, tar, out, B);
}